// Round 1
// baseline (2121.999 us; speedup 1.0000x reference)
//
#include <hip/hip_runtime.h>

#define NN 100000      // nodes
#define NE 1600000     // edges
// dims: NODE_IN=64, EDGE_DIM=32, NODE_OUT=64, concat=96, fused K=160

// ws float layout
#define OFF_G     0                    // NN*96 accumulated concat sums
#define OFF_CNT   (NN*96)              // NN   in-degree (float)
#define OFF_INV   (OFF_CNT + NN)       // NN   1/cnt or 0
#define OFF_MASK  (OFF_INV + NN)       // NN   cnt>0 ? 1 : 0
#define OFF_WCOMB (OFF_MASK + NN)      // 160*64 = [Wa_top(64x64); Wm@Wa_bot(96x64)]
#define OFF_BMW   (OFF_WCOMB + 160*64) // 64   bm@Wa_bot

// ---- edge scatter: g[dst] += concat(nfeats[src], efeats) ----------------
// 16 lanes per edge, each handles one float4 of the 64-dim nfeats row.
__global__ __launch_bounds__(256) void k_edge_nf(
    const float4* __restrict__ nf4, const int* __restrict__ src,
    const int* __restrict__ dst, float* __restrict__ g) {
  int tid = blockIdx.x * 256 + threadIdx.x;   // grid covers NE*16 exactly
  int e = tid >> 4, q = tid & 15;
  int s = src[e], d = dst[e];
  float4 v = nf4[s * 16 + q];
  float* gp = g + d * 96 + q * 4;
  atomicAdd(gp + 0, v.x); atomicAdd(gp + 1, v.y);
  atomicAdd(gp + 2, v.z); atomicAdd(gp + 3, v.w);
}

// 8 lanes per edge for the 32-dim efeats row; lane 0 also counts the edge.
__global__ __launch_bounds__(256) void k_edge_ef(
    const float4* __restrict__ ef4, const int* __restrict__ dst,
    float* __restrict__ g, float* __restrict__ cnt) {
  int tid = blockIdx.x * 256 + threadIdx.x;   // grid covers NE*8 exactly
  int e = tid >> 3, q = tid & 7;
  int d = dst[e];
  float4 v = ef4[e * 8 + q];
  float* gp = g + d * 96 + 64 + q * 4;
  atomicAdd(gp + 0, v.x); atomicAdd(gp + 1, v.y);
  atomicAdd(gp + 2, v.z); atomicAdd(gp + 3, v.w);
  if (q == 0) atomicAdd(cnt + d, 1.0f);
}

// ---- precompute fused weights: Wcomb = [Wa[0:64]; Wm @ Wa[64:128]], bmW = bm @ Wa[64:128]
__global__ __launch_bounds__(256) void k_pre1(
    const float* __restrict__ Wm, const float* __restrict__ bm,
    const float* __restrict__ Wa, float* __restrict__ Wcomb,
    float* __restrict__ bmW) {
  int b = blockIdx.x, t = threadIdx.x;
  if (b < 24) {                       // 24*256 = 6144 = 96*64 fused entries
    int o = b * 256 + t;
    int k = o >> 6, j = o & 63;
    float acc = 0.f;
    for (int kk = 0; kk < 64; ++kk)
      acc += Wm[k * 64 + kk] * Wa[(64 + kk) * 64 + j];
    Wcomb[(64 + k) * 64 + j] = acc;
  } else {
    for (int i = t; i < 64 * 64; i += 256) Wcomb[i] = Wa[i];  // top block copy
    if (t < 64) {
      float acc = 0.f;
      for (int kk = 0; kk < 64; ++kk) acc += bm[kk] * Wa[(64 + kk) * 64 + t];
      bmW[t] = acc;
    }
  }
}

// ---- per-node 1/cnt and isolated-node mask ----
__global__ __launch_bounds__(256) void k_pre2(
    const float* __restrict__ cnt, float* __restrict__ invc,
    float* __restrict__ mask) {
  int n = blockIdx.x * 256 + threadIdx.x;
  if (n < NN) {
    float c = cnt[n];
    bool nz = c > 0.f;
    invc[n] = nz ? 1.f / c : 0.f;
    mask[n] = nz ? 1.f : 0.f;
  }
}

// ---- fused node GEMM: out = relu([nf | g*inv] @ Wcomb + ba + mask*bmW) ----
// block: 128 nodes x 64 outs; thread: 4 nodes x 8 outs; K=160 in 5 chunks of 32.
__global__ __launch_bounds__(256) void k_main(
    const float4* __restrict__ nf4, const float4* __restrict__ g4,
    const float* __restrict__ invc, const float* __restrict__ mask,
    const float4* __restrict__ Wcomb4, const float* __restrict__ bmW,
    const float* __restrict__ ba, float* __restrict__ out) {
  __shared__ float sA[128 * 33];   // [node][k] pad 33 -> a-reads conflict-free
  __shared__ float sB[32 * 64];    // [k][j]
  int tid = threadIdx.x;
  int ty = tid >> 3, tx = tid & 7;
  int nbase = blockIdx.x * 128;
  float acc[4][8];
#pragma unroll
  for (int r = 0; r < 4; ++r)
#pragma unroll
    for (int e = 0; e < 8; ++e) acc[r][e] = 0.f;

  for (int c = 0; c < 5; ++c) {
    // stage A: 128 nodes x 32 k (chunks 0-1 from nfeats, 2-4 from g*inv)
#pragma unroll
    for (int i = 0; i < 4; ++i) {
      int f = i * 256 + tid;          // 0..1023 float4s
      int nl = f >> 3, q = f & 7;
      int node = nbase + nl; if (node > NN - 1) node = NN - 1;
      float4 v;
      if (c < 2) {
        v = nf4[node * 16 + c * 8 + q];
      } else {
        v = g4[node * 24 + (c - 2) * 8 + q];
        float iv = invc[node];
        v.x *= iv; v.y *= iv; v.z *= iv; v.w *= iv;
      }
      float* p = &sA[nl * 33 + q * 4];
      p[0] = v.x; p[1] = v.y; p[2] = v.z; p[3] = v.w;
    }
    // stage B: rows c*32..c*32+32 of Wcomb
#pragma unroll
    for (int i = 0; i < 2; ++i) {
      int f = i * 256 + tid;          // 0..511 float4s
      int kk = f >> 4, j4 = f & 15;
      float4 w = Wcomb4[(c * 32 + kk) * 16 + j4];
      *(float4*)&sB[kk * 64 + j4 * 4] = w;
    }
    __syncthreads();
#pragma unroll 8
    for (int kk = 0; kk < 32; ++kk) {
      float4 b0 = *(const float4*)&sB[kk * 64 + tx * 8];
      float4 b1 = *(const float4*)&sB[kk * 64 + tx * 8 + 4];
#pragma unroll
      for (int r = 0; r < 4; ++r) {
        float a = sA[(ty * 4 + r) * 33 + kk];
        acc[r][0] += a * b0.x; acc[r][1] += a * b0.y;
        acc[r][2] += a * b0.z; acc[r][3] += a * b0.w;
        acc[r][4] += a * b1.x; acc[r][5] += a * b1.y;
        acc[r][6] += a * b1.z; acc[r][7] += a * b1.w;
      }
    }
    __syncthreads();
  }
  // epilogue: + ba + mask*bmW, relu, store
  float4 ba0 = ((const float4*)ba)[tx * 2];
  float4 ba1 = ((const float4*)ba)[tx * 2 + 1];
  float4 bw0 = ((const float4*)bmW)[tx * 2];
  float4 bw1 = ((const float4*)bmW)[tx * 2 + 1];
#pragma unroll
  for (int r = 0; r < 4; ++r) {
    int node = nbase + ty * 4 + r;
    if (node < NN) {
      float mk = mask[node];
      float4 o0, o1;
      o0.x = acc[r][0] + ba0.x + mk * bw0.x;
      o0.y = acc[r][1] + ba0.y + mk * bw0.y;
      o0.z = acc[r][2] + ba0.z + mk * bw0.z;
      o0.w = acc[r][3] + ba0.w + mk * bw0.w;
      o1.x = acc[r][4] + ba1.x + mk * bw1.x;
      o1.y = acc[r][5] + ba1.y + mk * bw1.y;
      o1.z = acc[r][6] + ba1.z + mk * bw1.z;
      o1.w = acc[r][7] + ba1.w + mk * bw1.w;
      o0.x = fmaxf(o0.x, 0.f); o0.y = fmaxf(o0.y, 0.f);
      o0.z = fmaxf(o0.z, 0.f); o0.w = fmaxf(o0.w, 0.f);
      o1.x = fmaxf(o1.x, 0.f); o1.y = fmaxf(o1.y, 0.f);
      o1.z = fmaxf(o1.z, 0.f); o1.w = fmaxf(o1.w, 0.f);
      *(float4*)&out[node * 64 + tx * 8] = o0;
      *(float4*)&out[node * 64 + tx * 8 + 4] = o1;
    }
  }
}

extern "C" void kernel_launch(void* const* d_in, const int* in_sizes, int n_in,
                              void* d_out, int out_size, void* d_ws, size_t ws_size,
                              hipStream_t stream) {
  const float* nf = (const float*)d_in[0];
  const float* ef = (const float*)d_in[1];
  const int*   src = (const int*)d_in[2];
  const int*   dst = (const int*)d_in[3];
  const float* Wm = (const float*)d_in[4];
  const float* bm = (const float*)d_in[5];
  const float* Wa = (const float*)d_in[6];
  const float* ba = (const float*)d_in[7];
  float* ws = (float*)d_ws;
  float* g     = ws + OFF_G;
  float* cnt   = ws + OFF_CNT;
  float* invc  = ws + OFF_INV;
  float* mask  = ws + OFF_MASK;
  float* Wcomb = ws + OFF_WCOMB;
  float* bmW   = ws + OFF_BMW;
  float* out = (float*)d_out;

  // zero accumulators (g + cnt)
  hipMemsetAsync(d_ws, 0, (size_t)(NN * 96 + NN) * sizeof(float), stream);

  k_pre1<<<25, 256, 0, stream>>>(Wm, bm, Wa, Wcomb, bmW);
  k_edge_nf<<<NE * 16 / 256, 256, 0, stream>>>((const float4*)nf, src, dst, g);
  k_edge_ef<<<NE * 8 / 256, 256, 0, stream>>>((const float4*)ef, dst, g, cnt);
  k_pre2<<<(NN + 255) / 256, 256, 0, stream>>>(cnt, invc, mask);
  k_main<<<(NN + 127) / 128, 256, 0, stream>>>(
      (const float4*)nf, (const float4*)g, invc, mask,
      (const float4*)Wcomb, bmW, ba, out);
}

// Round 2
// 431.660 us; speedup vs baseline: 4.9159x; 4.9159x over previous
//
#include <hip/hip_runtime.h>

#define NN 100000      // nodes
#define NE 1600000     // edges
#define NBLK 391       // ceil(NN/256) scan blocks
// dims: NODE_IN=64, EDGE_DIM=32, NODE_OUT=64, concat=96, fused K=160

// ws layout (int/float elements, 4B each)
#define OFF_CNT   0                    // NN    int   in-degree (memset 0)
#define OFF_RS    100000               // NN+1  int   CSR row_start (exclusive)
#define OFF_CUR   200004               // NN    int   scatter cursors
#define OFF_BSUM  300008               // 512   int   per-block sums -> exclusive offsets
#define OFF_ESRC  300520               // NE    int   src sorted by dst
#define OFF_EEID  1900520              // NE    int   edge id sorted by dst
#define OFF_G     3500520              // NN*96 float accumulated concat sums (16B aligned)
#define OFF_WCOMB 13100520             // 160*64 float [Wa_top(64x64); Wm@Wa_bot(96x64)]
#define OFF_BMW   13110760             // 64    float bm@Wa_bot
#define OFF_INV   13110824             // NN    float 1/cnt or 0
#define OFF_MASK  13210824             // NN    float cnt>0 ? 1 : 0

// ---- 1. histogram of dst ------------------------------------------------
__global__ __launch_bounds__(256) void k_hist(const int* __restrict__ dst,
                                              int* __restrict__ cnt) {
  int e = blockIdx.x * 256 + threadIdx.x;   // grid covers NE exactly
  atomicAdd(&cnt[dst[e]], 1);
}

// ---- 2a. per-block inclusive scan + block sums --------------------------
__global__ __launch_bounds__(256) void k_scan1(const int* __restrict__ cnt,
                                               int* __restrict__ rs_incl,
                                               int* __restrict__ bsum) {
  __shared__ int s[256];
  int t = threadIdx.x, n = blockIdx.x * 256 + t;
  int v = (n < NN) ? cnt[n] : 0;
  s[t] = v; __syncthreads();
#pragma unroll
  for (int off = 1; off < 256; off <<= 1) {
    int x = (t >= off) ? s[t - off] : 0;
    __syncthreads();
    s[t] += x;
    __syncthreads();
  }
  if (n < NN) rs_incl[n] = s[t];
  if (t == 255) bsum[blockIdx.x] = s[255];
}

// ---- 2b. scan of block sums (one block of 512) --------------------------
__global__ __launch_bounds__(512) void k_scan2(int* __restrict__ bsum) {
  __shared__ int s[512];
  int t = threadIdx.x;
  int v = (t < NBLK) ? bsum[t] : 0;
  s[t] = v; __syncthreads();
#pragma unroll
  for (int off = 1; off < 512; off <<= 1) {
    int x = (t >= off) ? s[t - off] : 0;
    __syncthreads();
    s[t] += x;
    __syncthreads();
  }
  if (t < NBLK) bsum[t] = s[t] - v;   // exclusive
}

// ---- 2c. finalize exclusive row_start + cursors -------------------------
__global__ __launch_bounds__(256) void k_scan3(const int* __restrict__ cnt,
                                               const int* __restrict__ bsum,
                                               int* __restrict__ rs,
                                               int* __restrict__ cur) {
  int t = threadIdx.x, n = blockIdx.x * 256 + t;
  if (n < NN) {
    int excl = bsum[blockIdx.x] + rs[n] - cnt[n];
    rs[n] = excl;
    cur[n] = excl;
  }
  if (n == 0) rs[NN] = NE;
}

// ---- 3. scatter edges into dst-sorted order -----------------------------
__global__ __launch_bounds__(256) void k_scatter(const int* __restrict__ src,
                                                 const int* __restrict__ dst,
                                                 int* __restrict__ cur,
                                                 int* __restrict__ esrc,
                                                 int* __restrict__ eeid) {
  int e = blockIdx.x * 256 + threadIdx.x;   // grid covers NE exactly
  int d = dst[e];
  int pos = atomicAdd(&cur[d], 1);
  esrc[pos] = src[e];
  eeid[pos] = e;
}

// ---- 4. gather: one wave per node, lane = feature dim -------------------
__global__ __launch_bounds__(256) void k_gather(
    const float* __restrict__ nf, const float* __restrict__ ef,
    const int* __restrict__ esrc, const int* __restrict__ eeid,
    const int* __restrict__ rs, float* __restrict__ g) {
  int wid = threadIdx.x >> 6, lane = threadIdx.x & 63;
  int node = blockIdx.x * 4 + wid;          // 25000*4 == NN exactly
  int beg = rs[node], end = rs[node + 1];
  float a0 = 0.f, a1 = 0.f;
  int i = beg;
  for (; i + 1 < end; i += 2) {             // unroll 2: break latency chain
    int s0 = esrc[i], s1 = esrc[i + 1];
    a0 += nf[s0 * 64 + lane];
    a0 += nf[s1 * 64 + lane];
    if (lane < 32) {
      int e0 = eeid[i], e1 = eeid[i + 1];
      a1 += ef[e0 * 32 + lane];
      a1 += ef[e1 * 32 + lane];
    }
  }
  if (i < end) {
    int s0 = esrc[i];
    a0 += nf[s0 * 64 + lane];
    if (lane < 32) { int e0 = eeid[i]; a1 += ef[e0 * 32 + lane]; }
  }
  g[node * 96 + lane] = a0;
  if (lane < 32) g[node * 96 + 64 + lane] = a1;
}

// ---- precompute fused weights: Wcomb = [Wa[0:64]; Wm @ Wa[64:128]] ------
__global__ __launch_bounds__(256) void k_pre1(
    const float* __restrict__ Wm, const float* __restrict__ bm,
    const float* __restrict__ Wa, float* __restrict__ Wcomb,
    float* __restrict__ bmW) {
  int b = blockIdx.x, t = threadIdx.x;
  if (b < 24) {                       // 24*256 = 6144 = 96*64 fused entries
    int o = b * 256 + t;
    int k = o >> 6, j = o & 63;
    float acc = 0.f;
    for (int kk = 0; kk < 64; ++kk)
      acc += Wm[k * 64 + kk] * Wa[(64 + kk) * 64 + j];
    Wcomb[(64 + k) * 64 + j] = acc;
  } else {
    for (int i = t; i < 64 * 64; i += 256) Wcomb[i] = Wa[i];  // top block copy
    if (t < 64) {
      float acc = 0.f;
      for (int kk = 0; kk < 64; ++kk) acc += bm[kk] * Wa[(64 + kk) * 64 + t];
      bmW[t] = acc;
    }
  }
}

// ---- per-node 1/cnt and isolated-node mask ------------------------------
__global__ __launch_bounds__(256) void k_pre2(
    const int* __restrict__ cnt, float* __restrict__ invc,
    float* __restrict__ mask) {
  int n = blockIdx.x * 256 + threadIdx.x;
  if (n < NN) {
    int c = cnt[n];
    invc[n] = c ? 1.f / (float)c : 0.f;
    mask[n] = c ? 1.f : 0.f;
  }
}

// ---- fused node GEMM: out = relu([nf | g*inv] @ Wcomb + ba + mask*bmW) --
// block: 128 nodes x 64 outs; thread: 4 nodes x 8 outs; K=160 in 5 chunks of 32.
__global__ __launch_bounds__(256) void k_main(
    const float4* __restrict__ nf4, const float4* __restrict__ g4,
    const float* __restrict__ invc, const float* __restrict__ mask,
    const float4* __restrict__ Wcomb4, const float* __restrict__ bmW,
    const float* __restrict__ ba, float* __restrict__ out) {
  __shared__ float sA[128 * 33];   // [node][k] pad 33 -> a-reads conflict-free
  __shared__ float sB[32 * 64];    // [k][j]
  int tid = threadIdx.x;
  int ty = tid >> 3, tx = tid & 7;
  int nbase = blockIdx.x * 128;
  float acc[4][8];
#pragma unroll
  for (int r = 0; r < 4; ++r)
#pragma unroll
    for (int e = 0; e < 8; ++e) acc[r][e] = 0.f;

  for (int c = 0; c < 5; ++c) {
#pragma unroll
    for (int i = 0; i < 4; ++i) {
      int f = i * 256 + tid;          // 0..1023 float4s
      int nl = f >> 3, q = f & 7;
      int node = nbase + nl; if (node > NN - 1) node = NN - 1;
      float4 v;
      if (c < 2) {
        v = nf4[node * 16 + c * 8 + q];
      } else {
        v = g4[node * 24 + (c - 2) * 8 + q];
        float iv = invc[node];
        v.x *= iv; v.y *= iv; v.z *= iv; v.w *= iv;
      }
      float* p = &sA[nl * 33 + q * 4];
      p[0] = v.x; p[1] = v.y; p[2] = v.z; p[3] = v.w;
    }
#pragma unroll
    for (int i = 0; i < 2; ++i) {
      int f = i * 256 + tid;          // 0..511 float4s
      int kk = f >> 4, j4 = f & 15;
      float4 w = Wcomb4[(c * 32 + kk) * 16 + j4];
      *(float4*)&sB[kk * 64 + j4 * 4] = w;
    }
    __syncthreads();
#pragma unroll 8
    for (int kk = 0; kk < 32; ++kk) {
      float4 b0 = *(const float4*)&sB[kk * 64 + tx * 8];
      float4 b1 = *(const float4*)&sB[kk * 64 + tx * 8 + 4];
#pragma unroll
      for (int r = 0; r < 4; ++r) {
        float a = sA[(ty * 4 + r) * 33 + kk];
        acc[r][0] += a * b0.x; acc[r][1] += a * b0.y;
        acc[r][2] += a * b0.z; acc[r][3] += a * b0.w;
        acc[r][4] += a * b1.x; acc[r][5] += a * b1.y;
        acc[r][6] += a * b1.z; acc[r][7] += a * b1.w;
      }
    }
    __syncthreads();
  }
  float4 ba0 = ((const float4*)ba)[tx * 2];
  float4 ba1 = ((const float4*)ba)[tx * 2 + 1];
  float4 bw0 = ((const float4*)bmW)[tx * 2];
  float4 bw1 = ((const float4*)bmW)[tx * 2 + 1];
#pragma unroll
  for (int r = 0; r < 4; ++r) {
    int node = nbase + ty * 4 + r;
    if (node < NN) {
      float mk = mask[node];
      float4 o0, o1;
      o0.x = acc[r][0] + ba0.x + mk * bw0.x;
      o0.y = acc[r][1] + ba0.y + mk * bw0.y;
      o0.z = acc[r][2] + ba0.z + mk * bw0.z;
      o0.w = acc[r][3] + ba0.w + mk * bw0.w;
      o1.x = acc[r][4] + ba1.x + mk * bw1.x;
      o1.y = acc[r][5] + ba1.y + mk * bw1.y;
      o1.z = acc[r][6] + ba1.z + mk * bw1.z;
      o1.w = acc[r][7] + ba1.w + mk * bw1.w;
      o0.x = fmaxf(o0.x, 0.f); o0.y = fmaxf(o0.y, 0.f);
      o0.z = fmaxf(o0.z, 0.f); o0.w = fmaxf(o0.w, 0.f);
      o1.x = fmaxf(o1.x, 0.f); o1.y = fmaxf(o1.y, 0.f);
      o1.z = fmaxf(o1.z, 0.f); o1.w = fmaxf(o1.w, 0.f);
      *(float4*)&out[node * 64 + tx * 8] = o0;
      *(float4*)&out[node * 64 + tx * 8 + 4] = o1;
    }
  }
}

extern "C" void kernel_launch(void* const* d_in, const int* in_sizes, int n_in,
                              void* d_out, int out_size, void* d_ws, size_t ws_size,
                              hipStream_t stream) {
  const float* nf = (const float*)d_in[0];
  const float* ef = (const float*)d_in[1];
  const int*   src = (const int*)d_in[2];
  const int*   dst = (const int*)d_in[3];
  const float* Wm = (const float*)d_in[4];
  const float* bm = (const float*)d_in[5];
  const float* Wa = (const float*)d_in[6];
  const float* ba = (const float*)d_in[7];
  int*   wsi = (int*)d_ws;
  float* wsf = (float*)d_ws;
  int*   cnt   = wsi + OFF_CNT;
  int*   rs    = wsi + OFF_RS;
  int*   cur   = wsi + OFF_CUR;
  int*   bsum  = wsi + OFF_BSUM;
  int*   esrc  = wsi + OFF_ESRC;
  int*   eeid  = wsi + OFF_EEID;
  float* g     = wsf + OFF_G;
  float* Wcomb = wsf + OFF_WCOMB;
  float* bmW   = wsf + OFF_BMW;
  float* invc  = wsf + OFF_INV;
  float* mask  = wsf + OFF_MASK;
  float* out = (float*)d_out;

  hipMemsetAsync(cnt, 0, (size_t)NN * sizeof(int), stream);   // only histogram needs zeroing

  k_pre1<<<25, 256, 0, stream>>>(Wm, bm, Wa, Wcomb, bmW);
  k_hist<<<NE / 256, 256, 0, stream>>>(dst, cnt);
  k_scan1<<<NBLK, 256, 0, stream>>>(cnt, rs, bsum);
  k_scan2<<<1, 512, 0, stream>>>(bsum);
  k_scan3<<<NBLK, 256, 0, stream>>>(cnt, bsum, rs, cur);
  k_scatter<<<NE / 256, 256, 0, stream>>>(src, dst, cur, esrc, eeid);
  k_gather<<<NN / 4, 256, 0, stream>>>(nf, ef, esrc, eeid, rs, g);
  k_pre2<<<(NN + 255) / 256, 256, 0, stream>>>(cnt, invc, mask);
  k_main<<<(NN + 127) / 128, 256, 0, stream>>>(
      (const float4*)nf, (const float4*)g, invc, mask,
      (const float4*)Wcomb, bmW, ba, out);
}

// Round 3
// 329.314 us; speedup vs baseline: 6.4437x; 1.3108x over previous
//
#include <hip/hip_runtime.h>

#define NN 100000      // nodes
#define NE 1600000     // edges
#define NBLK 391       // ceil(NN/256) scan blocks
// dims: NODE_IN=64, EDGE_DIM=32, NODE_OUT=64, concat=96, fused K=160

// ws layout (4B units)
#define OFF_CNT   0                    // NN    int   in-degree (memset 0)
#define OFF_RS    100000               // NN+1  int   CSR row_start (exclusive)
#define OFF_CUR   200004               // NN    int   scatter cursors
#define OFF_BSUM  300008               // 512   int   per-block sums -> exclusive offsets
#define OFF_EINFO 300520               // NE*2  int2  (src, eid) sorted by dst (8B aligned)
#define OFF_G     3500520              // NN*96 float concat sums (16B aligned)
#define OFF_WCOMB 13100520             // 160*64 float [Wa_top(64x64); Wm@Wa_bot(96x64)]
#define OFF_BMW   13110760             // 64    float bm@Wa_bot
#define OFF_INV   13110824             // NN    float 1/cnt or 0
#define OFF_MASK  13210824             // NN    float cnt>0 ? 1 : 0

// ---- 1. histogram of dst ------------------------------------------------
__global__ __launch_bounds__(256) void k_hist(const int* __restrict__ dst,
                                              int* __restrict__ cnt) {
  int e = blockIdx.x * 256 + threadIdx.x;   // grid covers NE exactly
  atomicAdd(&cnt[dst[e]], 1);
}

// ---- 2a. per-block inclusive scan + block sums --------------------------
__global__ __launch_bounds__(256) void k_scan1(const int* __restrict__ cnt,
                                               int* __restrict__ rs_incl,
                                               int* __restrict__ bsum) {
  __shared__ int s[256];
  int t = threadIdx.x, n = blockIdx.x * 256 + t;
  int v = (n < NN) ? cnt[n] : 0;
  s[t] = v; __syncthreads();
#pragma unroll
  for (int off = 1; off < 256; off <<= 1) {
    int x = (t >= off) ? s[t - off] : 0;
    __syncthreads();
    s[t] += x;
    __syncthreads();
  }
  if (n < NN) rs_incl[n] = s[t];
  if (t == 255) bsum[blockIdx.x] = s[255];
}

// ---- 2b. scan of block sums (one block of 512) --------------------------
__global__ __launch_bounds__(512) void k_scan2(int* __restrict__ bsum) {
  __shared__ int s[512];
  int t = threadIdx.x;
  int v = (t < NBLK) ? bsum[t] : 0;
  s[t] = v; __syncthreads();
#pragma unroll
  for (int off = 1; off < 512; off <<= 1) {
    int x = (t >= off) ? s[t - off] : 0;
    __syncthreads();
    s[t] += x;
    __syncthreads();
  }
  if (t < NBLK) bsum[t] = s[t] - v;   // exclusive
}

// ---- 2c. finalize row_start + cursors + invc/mask (fused pre2) ----------
__global__ __launch_bounds__(256) void k_scan3(const int* __restrict__ cnt,
                                               const int* __restrict__ bsum,
                                               int* __restrict__ rs,
                                               int* __restrict__ cur,
                                               float* __restrict__ invc,
                                               float* __restrict__ mask) {
  int t = threadIdx.x, n = blockIdx.x * 256 + t;
  if (n < NN) {
    int c = cnt[n];
    int excl = bsum[blockIdx.x] + rs[n] - c;
    rs[n] = excl;
    cur[n] = excl;
    invc[n] = c ? 1.f / (float)c : 0.f;
    mask[n] = c ? 1.f : 0.f;
  }
  if (n == 0) rs[NN] = NE;
}

// ---- 3. scatter (src, eid) into dst-sorted order ------------------------
__global__ __launch_bounds__(256) void k_scatter(const int* __restrict__ src,
                                                 const int* __restrict__ dst,
                                                 int* __restrict__ cur,
                                                 int2* __restrict__ einfo) {
  int e = blockIdx.x * 256 + threadIdx.x;   // grid covers NE exactly
  int d = dst[e];
  int pos = atomicAdd(&cur[d], 1);
  einfo[pos] = make_int2(src[e], e);
}

// ---- 4. gather: one wave per node, lane = feature dim -------------------
// Indices batch-loaded (one coalesced int2 load per 64 edges), broadcast via
// shfl. ef loads paired across wave halves (lane<32 -> edge j, lane>=32 ->
// edge j+1) so all 64 lanes load every cycle. 4-edge unroll for MLP.
__global__ __launch_bounds__(256) void k_gather(
    const float* __restrict__ nf, const float* __restrict__ ef,
    const int2* __restrict__ einfo, const int* __restrict__ rs,
    float* __restrict__ g) {
  int wid = threadIdx.x >> 6, lane = threadIdx.x & 63;
  int node = blockIdx.x * 4 + wid;          // 25000*4 == NN exactly
  int beg = rs[node], end = rs[node + 1];
  int deg = end - beg;
  bool hi = lane >= 32;
  int l32 = lane & 31;
  float a0 = 0.f, a1 = 0.f;
  for (int base = 0; base < deg; base += 64) {
    int nb = deg - base; if (nb > 64) nb = 64;
    int2 info = (lane < nb) ? einfo[beg + base + lane] : make_int2(0, 0);
    int j = 0;
    for (; j + 4 <= nb; j += 4) {
      int s0 = __shfl(info.x, j);
      int s1 = __shfl(info.x, j + 1);
      int s2 = __shfl(info.x, j + 2);
      int s3 = __shfl(info.x, j + 3);
      int ep0 = __shfl(info.y, hi ? j + 1 : j);
      int ep1 = __shfl(info.y, hi ? j + 3 : j + 2);
      float v0 = nf[s0 * 64 + lane];
      float v1 = nf[s1 * 64 + lane];
      float v2 = nf[s2 * 64 + lane];
      float v3 = nf[s3 * 64 + lane];
      float w0 = ef[ep0 * 32 + l32];
      float w1 = ef[ep1 * 32 + l32];
      a0 += v0 + v1 + v2 + v3;
      a1 += w0 + w1;
    }
    for (; j + 2 <= nb; j += 2) {
      int s0 = __shfl(info.x, j);
      int s1 = __shfl(info.x, j + 1);
      int ep = __shfl(info.y, hi ? j + 1 : j);
      float v0 = nf[s0 * 64 + lane];
      float v1 = nf[s1 * 64 + lane];
      float w0 = ef[ep * 32 + l32];
      a0 += v0 + v1;
      a1 += w0;
    }
    if (j < nb) {
      int s0 = __shfl(info.x, j);
      int e0 = __shfl(info.y, j);
      a0 += nf[s0 * 64 + lane];
      if (!hi) a1 += ef[e0 * 32 + l32];
    }
  }
  a1 += __shfl_down(a1, 32);     // fold odd-edge ef sums (upper half) into lower
  g[node * 96 + lane] = a0;
  if (!hi) g[node * 96 + 64 + l32] = a1;
}

// ---- precompute fused weights: Wcomb = [Wa[0:64]; Wm @ Wa[64:128]] ------
__global__ __launch_bounds__(256) void k_pre1(
    const float* __restrict__ Wm, const float* __restrict__ bm,
    const float* __restrict__ Wa, float* __restrict__ Wcomb,
    float* __restrict__ bmW) {
  int b = blockIdx.x, t = threadIdx.x;
  if (b < 24) {                       // 24*256 = 6144 = 96*64 fused entries
    int o = b * 256 + t;
    int k = o >> 6, j = o & 63;
    float acc = 0.f;
    for (int kk = 0; kk < 64; ++kk)
      acc += Wm[k * 64 + kk] * Wa[(64 + kk) * 64 + j];
    Wcomb[(64 + k) * 64 + j] = acc;
  } else {
    for (int i = t; i < 64 * 64; i += 256) Wcomb[i] = Wa[i];  // top block copy
    if (t < 64) {
      float acc = 0.f;
      for (int kk = 0; kk < 64; ++kk) acc += bm[kk] * Wa[(64 + kk) * 64 + t];
      bmW[t] = acc;
    }
  }
}

// ---- fused node GEMM: out = relu([nf | g*inv] @ Wcomb + ba + mask*bmW) --
// block: 128 nodes x 64 outs; thread: 4 nodes x 8 outs; K=160 in 5 chunks of 32.
__global__ __launch_bounds__(256) void k_main(
    const float4* __restrict__ nf4, const float4* __restrict__ g4,
    const float* __restrict__ invc, const float* __restrict__ mask,
    const float4* __restrict__ Wcomb4, const float* __restrict__ bmW,
    const float* __restrict__ ba, float* __restrict__ out) {
  __shared__ float sA[128 * 33];   // [node][k] pad 33 -> a-reads conflict-free
  __shared__ float sB[32 * 64];    // [k][j]
  int tid = threadIdx.x;
  int ty = tid >> 3, tx = tid & 7;
  int nbase = blockIdx.x * 128;
  float acc[4][8];
#pragma unroll
  for (int r = 0; r < 4; ++r)
#pragma unroll
    for (int e = 0; e < 8; ++e) acc[r][e] = 0.f;

  for (int c = 0; c < 5; ++c) {
#pragma unroll
    for (int i = 0; i < 4; ++i) {
      int f = i * 256 + tid;          // 0..1023 float4s
      int nl = f >> 3, q = f & 7;
      int node = nbase + nl; if (node > NN - 1) node = NN - 1;
      float4 v;
      if (c < 2) {
        v = nf4[node * 16 + c * 8 + q];
      } else {
        v = g4[node * 24 + (c - 2) * 8 + q];
        float iv = invc[node];
        v.x *= iv; v.y *= iv; v.z *= iv; v.w *= iv;
      }
      float* p = &sA[nl * 33 + q * 4];
      p[0] = v.x; p[1] = v.y; p[2] = v.z; p[3] = v.w;
    }
#pragma unroll
    for (int i = 0; i < 2; ++i) {
      int f = i * 256 + tid;          // 0..511 float4s
      int kk = f >> 4, j4 = f & 15;
      float4 w = Wcomb4[(c * 32 + kk) * 16 + j4];
      *(float4*)&sB[kk * 64 + j4 * 4] = w;
    }
    __syncthreads();
#pragma unroll 8
    for (int kk = 0; kk < 32; ++kk) {
      float4 b0 = *(const float4*)&sB[kk * 64 + tx * 8];
      float4 b1 = *(const float4*)&sB[kk * 64 + tx * 8 + 4];
#pragma unroll
      for (int r = 0; r < 4; ++r) {
        float a = sA[(ty * 4 + r) * 33 + kk];
        acc[r][0] += a * b0.x; acc[r][1] += a * b0.y;
        acc[r][2] += a * b0.z; acc[r][3] += a * b0.w;
        acc[r][4] += a * b1.x; acc[r][5] += a * b1.y;
        acc[r][6] += a * b1.z; acc[r][7] += a * b1.w;
      }
    }
    __syncthreads();
  }
  float4 ba0 = ((const float4*)ba)[tx * 2];
  float4 ba1 = ((const float4*)ba)[tx * 2 + 1];
  float4 bw0 = ((const float4*)bmW)[tx * 2];
  float4 bw1 = ((const float4*)bmW)[tx * 2 + 1];
#pragma unroll
  for (int r = 0; r < 4; ++r) {
    int node = nbase + ty * 4 + r;
    if (node < NN) {
      float mk = mask[node];
      float4 o0, o1;
      o0.x = acc[r][0] + ba0.x + mk * bw0.x;
      o0.y = acc[r][1] + ba0.y + mk * bw0.y;
      o0.z = acc[r][2] + ba0.z + mk * bw0.z;
      o0.w = acc[r][3] + ba0.w + mk * bw0.w;
      o1.x = acc[r][4] + ba1.x + mk * bw1.x;
      o1.y = acc[r][5] + ba1.y + mk * bw1.y;
      o1.z = acc[r][6] + ba1.z + mk * bw1.z;
      o1.w = acc[r][7] + ba1.w + mk * bw1.w;
      o0.x = fmaxf(o0.x, 0.f); o0.y = fmaxf(o0.y, 0.f);
      o0.z = fmaxf(o0.z, 0.f); o0.w = fmaxf(o0.w, 0.f);
      o1.x = fmaxf(o1.x, 0.f); o1.y = fmaxf(o1.y, 0.f);
      o1.z = fmaxf(o1.z, 0.f); o1.w = fmaxf(o1.w, 0.f);
      *(float4*)&out[node * 64 + tx * 8] = o0;
      *(float4*)&out[node * 64 + tx * 8 + 4] = o1;
    }
  }
}

extern "C" void kernel_launch(void* const* d_in, const int* in_sizes, int n_in,
                              void* d_out, int out_size, void* d_ws, size_t ws_size,
                              hipStream_t stream) {
  const float* nf = (const float*)d_in[0];
  const float* ef = (const float*)d_in[1];
  const int*   src = (const int*)d_in[2];
  const int*   dst = (const int*)d_in[3];
  const float* Wm = (const float*)d_in[4];
  const float* bm = (const float*)d_in[5];
  const float* Wa = (const float*)d_in[6];
  const float* ba = (const float*)d_in[7];
  int*   wsi = (int*)d_ws;
  float* wsf = (float*)d_ws;
  int*   cnt   = wsi + OFF_CNT;
  int*   rs    = wsi + OFF_RS;
  int*   cur   = wsi + OFF_CUR;
  int*   bsum  = wsi + OFF_BSUM;
  int2*  einfo = (int2*)(wsi + OFF_EINFO);
  float* g     = wsf + OFF_G;
  float* Wcomb = wsf + OFF_WCOMB;
  float* bmW   = wsf + OFF_BMW;
  float* invc  = wsf + OFF_INV;
  float* mask  = wsf + OFF_MASK;
  float* out = (float*)d_out;

  hipMemsetAsync(cnt, 0, (size_t)NN * sizeof(int), stream);   // only histogram needs zeroing

  k_pre1<<<25, 256, 0, stream>>>(Wm, bm, Wa, Wcomb, bmW);
  k_hist<<<NE / 256, 256, 0, stream>>>(dst, cnt);
  k_scan1<<<NBLK, 256, 0, stream>>>(cnt, rs, bsum);
  k_scan2<<<1, 512, 0, stream>>>(bsum);
  k_scan3<<<NBLK, 256, 0, stream>>>(cnt, bsum, rs, cur, invc, mask);
  k_scatter<<<NE / 256, 256, 0, stream>>>(src, dst, cur, einfo);
  k_gather<<<NN / 4, 256, 0, stream>>>(nf, ef, einfo, rs, g);
  k_main<<<(NN + 127) / 128, 256, 0, stream>>>(
      (const float4*)nf, (const float4*)g, invc, mask,
      (const float4*)Wcomb, bmW, ba, out);
}

// Round 4
// 317.008 us; speedup vs baseline: 6.6938x; 1.0388x over previous
//
#include <hip/hip_runtime.h>

#define NN 100000      // nodes
#define NE 1600000     // edges
#define NBLK 391       // ceil(NN/256) scan blocks
// dims: NODE_IN=64, EDGE_DIM=32, NODE_OUT=64, concat=96, fused K=160

// ws layout (4B units)
#define OFF_CNT   0                    // NN    int   in-degree (memset 0)
#define OFF_RS    100000               // NN+1  int   CSR row_start (exclusive)
#define OFF_CUR   200004               // NN    int   scatter cursors
#define OFF_BSUM  300008               // 512   int   per-block sums -> exclusive offsets
#define OFF_EINFO 300520               // NE*2  int2  (src, eid) sorted by dst (8B aligned)
#define OFF_G     3500520              // NN*96 float concat sums (16B aligned)
#define OFF_WCOMB 13100520             // 160*64 float [Wa_top(64x64); Wm@Wa_bot(96x64)]
#define OFF_BMW   13110760             // 64    float bm@Wa_bot
#define OFF_INV   13110824             // NN    float 1/cnt or 0
#define OFF_MASK  13210824             // NN    float cnt>0 ? 1 : 0

// ---- 1. histogram of dst (8 edges/thread: 8 independent atomics in flight)
__global__ __launch_bounds__(256) void k_hist(const int4* __restrict__ dst4,
                                              int* __restrict__ cnt) {
  int t = blockIdx.x * 256 + threadIdx.x;
  if (t >= NE / 8) return;
  int4 d0 = dst4[t * 2], d1 = dst4[t * 2 + 1];
  atomicAdd(&cnt[d0.x], 1); atomicAdd(&cnt[d0.y], 1);
  atomicAdd(&cnt[d0.z], 1); atomicAdd(&cnt[d0.w], 1);
  atomicAdd(&cnt[d1.x], 1); atomicAdd(&cnt[d1.y], 1);
  atomicAdd(&cnt[d1.z], 1); atomicAdd(&cnt[d1.w], 1);
}

// ---- 2a. per-block inclusive scan + block sums --------------------------
__global__ __launch_bounds__(256) void k_scan1(const int* __restrict__ cnt,
                                               int* __restrict__ rs_incl,
                                               int* __restrict__ bsum) {
  __shared__ int s[256];
  int t = threadIdx.x, n = blockIdx.x * 256 + t;
  int v = (n < NN) ? cnt[n] : 0;
  s[t] = v; __syncthreads();
#pragma unroll
  for (int off = 1; off < 256; off <<= 1) {
    int x = (t >= off) ? s[t - off] : 0;
    __syncthreads();
    s[t] += x;
    __syncthreads();
  }
  if (n < NN) rs_incl[n] = s[t];
  if (t == 255) bsum[blockIdx.x] = s[255];
}

// ---- 2b. scan of block sums (one block of 512) --------------------------
__global__ __launch_bounds__(512) void k_scan2(int* __restrict__ bsum) {
  __shared__ int s[512];
  int t = threadIdx.x;
  int v = (t < NBLK) ? bsum[t] : 0;
  s[t] = v; __syncthreads();
#pragma unroll
  for (int off = 1; off < 512; off <<= 1) {
    int x = (t >= off) ? s[t - off] : 0;
    __syncthreads();
    s[t] += x;
    __syncthreads();
  }
  if (t < NBLK) bsum[t] = s[t] - v;   // exclusive
}

// ---- 2c. finalize row_start + cursors + invc/mask -----------------------
__global__ __launch_bounds__(256) void k_scan3(const int* __restrict__ cnt,
                                               const int* __restrict__ bsum,
                                               int* __restrict__ rs,
                                               int* __restrict__ cur,
                                               float* __restrict__ invc,
                                               float* __restrict__ mask) {
  int t = threadIdx.x, n = blockIdx.x * 256 + t;
  if (n < NN) {
    int c = cnt[n];
    int excl = bsum[blockIdx.x] + rs[n] - c;
    rs[n] = excl;
    cur[n] = excl;
    invc[n] = c ? 1.f / (float)c : 0.f;
    mask[n] = c ? 1.f : 0.f;
  }
  if (n == 0) rs[NN] = NE;
}

// ---- 3. scatter (src, eid) into dst-sorted order ------------------------
// 8 edges/thread: 8 independent atomic round-trips overlap, then 8 stores.
__global__ __launch_bounds__(256) void k_scatter(const int4* __restrict__ src4,
                                                 const int4* __restrict__ dst4,
                                                 int* __restrict__ cur,
                                                 int2* __restrict__ einfo) {
  int t = blockIdx.x * 256 + threadIdx.x;
  if (t >= NE / 8) return;
  int4 d0 = dst4[t * 2], d1 = dst4[t * 2 + 1];
  int4 s0 = src4[t * 2], s1 = src4[t * 2 + 1];
  int e = t * 8;
  int p0 = atomicAdd(&cur[d0.x], 1);
  int p1 = atomicAdd(&cur[d0.y], 1);
  int p2 = atomicAdd(&cur[d0.z], 1);
  int p3 = atomicAdd(&cur[d0.w], 1);
  int p4 = atomicAdd(&cur[d1.x], 1);
  int p5 = atomicAdd(&cur[d1.y], 1);
  int p6 = atomicAdd(&cur[d1.z], 1);
  int p7 = atomicAdd(&cur[d1.w], 1);
  einfo[p0] = make_int2(s0.x, e + 0);
  einfo[p1] = make_int2(s0.y, e + 1);
  einfo[p2] = make_int2(s0.z, e + 2);
  einfo[p3] = make_int2(s0.w, e + 3);
  einfo[p4] = make_int2(s1.x, e + 4);
  einfo[p5] = make_int2(s1.y, e + 5);
  einfo[p6] = make_int2(s1.z, e + 6);
  einfo[p7] = make_int2(s1.w, e + 7);
}

// ---- 4. gather: one wave per node, lane = feature dim -------------------
// Indices batch-loaded (one coalesced int2 load per 64 edges), broadcast via
// shfl. ef loads paired across wave halves. 8-edge unroll for MLP.
__global__ __launch_bounds__(256) void k_gather(
    const float* __restrict__ nf, const float* __restrict__ ef,
    const int2* __restrict__ einfo, const int* __restrict__ rs,
    float* __restrict__ g) {
  int wid = threadIdx.x >> 6, lane = threadIdx.x & 63;
  int node = blockIdx.x * 4 + wid;          // 25000*4 == NN exactly
  int beg = rs[node], end = rs[node + 1];
  int deg = end - beg;
  bool hi = lane >= 32;
  int l32 = lane & 31;
  float a0 = 0.f, a1 = 0.f;
  for (int base = 0; base < deg; base += 64) {
    int nb = deg - base; if (nb > 64) nb = 64;
    int2 info = (lane < nb) ? einfo[beg + base + lane] : make_int2(0, 0);
    int j = 0;
    for (; j + 8 <= nb; j += 8) {
      int s0 = __shfl(info.x, j);
      int s1 = __shfl(info.x, j + 1);
      int s2 = __shfl(info.x, j + 2);
      int s3 = __shfl(info.x, j + 3);
      int s4 = __shfl(info.x, j + 4);
      int s5 = __shfl(info.x, j + 5);
      int s6 = __shfl(info.x, j + 6);
      int s7 = __shfl(info.x, j + 7);
      int ep0 = __shfl(info.y, hi ? j + 1 : j);
      int ep1 = __shfl(info.y, hi ? j + 3 : j + 2);
      int ep2 = __shfl(info.y, hi ? j + 5 : j + 4);
      int ep3 = __shfl(info.y, hi ? j + 7 : j + 6);
      float v0 = nf[s0 * 64 + lane];
      float v1 = nf[s1 * 64 + lane];
      float v2 = nf[s2 * 64 + lane];
      float v3 = nf[s3 * 64 + lane];
      float v4 = nf[s4 * 64 + lane];
      float v5 = nf[s5 * 64 + lane];
      float v6 = nf[s6 * 64 + lane];
      float v7 = nf[s7 * 64 + lane];
      float w0 = ef[ep0 * 32 + l32];
      float w1 = ef[ep1 * 32 + l32];
      float w2 = ef[ep2 * 32 + l32];
      float w3 = ef[ep3 * 32 + l32];
      a0 += v0 + v1 + v2 + v3 + v4 + v5 + v6 + v7;
      a1 += w0 + w1 + w2 + w3;
    }
    for (; j + 2 <= nb; j += 2) {
      int s0 = __shfl(info.x, j);
      int s1 = __shfl(info.x, j + 1);
      int ep = __shfl(info.y, hi ? j + 1 : j);
      float v0 = nf[s0 * 64 + lane];
      float v1 = nf[s1 * 64 + lane];
      float w0 = ef[ep * 32 + l32];
      a0 += v0 + v1;
      a1 += w0;
    }
    if (j < nb) {
      int s0 = __shfl(info.x, j);
      int e0 = __shfl(info.y, j);
      a0 += nf[s0 * 64 + lane];
      if (!hi) a1 += ef[e0 * 32 + l32];
    }
  }
  a1 += __shfl_down(a1, 32);     // fold odd-edge ef sums (upper half) into lower
  g[node * 96 + lane] = a0;
  if (!hi) g[node * 96 + 64 + l32] = a1;
}

// ---- precompute fused weights: Wcomb = [Wa[0:64]; Wm @ Wa[64:128]] ------
__global__ __launch_bounds__(256) void k_pre1(
    const float* __restrict__ Wm, const float* __restrict__ bm,
    const float* __restrict__ Wa, float* __restrict__ Wcomb,
    float* __restrict__ bmW) {
  int b = blockIdx.x, t = threadIdx.x;
  if (b < 24) {                       // 24*256 = 6144 = 96*64 fused entries
    int o = b * 256 + t;
    int k = o >> 6, j = o & 63;
    float acc = 0.f;
    for (int kk = 0; kk < 64; ++kk)
      acc += Wm[k * 64 + kk] * Wa[(64 + kk) * 64 + j];
    Wcomb[(64 + k) * 64 + j] = acc;
  } else {
    for (int i = t; i < 64 * 64; i += 256) Wcomb[i] = Wa[i];  // top block copy
    if (t < 64) {
      float acc = 0.f;
      for (int kk = 0; kk < 64; ++kk) acc += bm[kk] * Wa[(64 + kk) * 64 + t];
      bmW[t] = acc;
    }
  }
}

// ---- fused node GEMM: out = relu([nf | g*inv] @ Wcomb + ba + mask*bmW) --
// block: 128 nodes x 64 outs; thread: 4 nodes x 8 outs; K=160 in 5 chunks of 32.
__global__ __launch_bounds__(256) void k_main(
    const float4* __restrict__ nf4, const float4* __restrict__ g4,
    const float* __restrict__ invc, const float* __restrict__ mask,
    const float4* __restrict__ Wcomb4, const float* __restrict__ bmW,
    const float* __restrict__ ba, float* __restrict__ out) {
  __shared__ float sA[128 * 33];   // [node][k] pad 33 -> a-reads conflict-free
  __shared__ float sB[32 * 64];    // [k][j]
  int tid = threadIdx.x;
  int ty = tid >> 3, tx = tid & 7;
  int nbase = blockIdx.x * 128;
  float acc[4][8];
#pragma unroll
  for (int r = 0; r < 4; ++r)
#pragma unroll
    for (int e = 0; e < 8; ++e) acc[r][e] = 0.f;

  for (int c = 0; c < 5; ++c) {
#pragma unroll
    for (int i = 0; i < 4; ++i) {
      int f = i * 256 + tid;          // 0..1023 float4s
      int nl = f >> 3, q = f & 7;
      int node = nbase + nl; if (node > NN - 1) node = NN - 1;
      float4 v;
      if (c < 2) {
        v = nf4[node * 16 + c * 8 + q];
      } else {
        v = g4[node * 24 + (c - 2) * 8 + q];
        float iv = invc[node];
        v.x *= iv; v.y *= iv; v.z *= iv; v.w *= iv;
      }
      float* p = &sA[nl * 33 + q * 4];
      p[0] = v.x; p[1] = v.y; p[2] = v.z; p[3] = v.w;
    }
#pragma unroll
    for (int i = 0; i < 2; ++i) {
      int f = i * 256 + tid;          // 0..511 float4s
      int kk = f >> 4, j4 = f & 15;
      float4 w = Wcomb4[(c * 32 + kk) * 16 + j4];
      *(float4*)&sB[kk * 64 + j4 * 4] = w;
    }
    __syncthreads();
#pragma unroll 8
    for (int kk = 0; kk < 32; ++kk) {
      float4 b0 = *(const float4*)&sB[kk * 64 + tx * 8];
      float4 b1 = *(const float4*)&sB[kk * 64 + tx * 8 + 4];
#pragma unroll
      for (int r = 0; r < 4; ++r) {
        float a = sA[(ty * 4 + r) * 33 + kk];
        acc[r][0] += a * b0.x; acc[r][1] += a * b0.y;
        acc[r][2] += a * b0.z; acc[r][3] += a * b0.w;
        acc[r][4] += a * b1.x; acc[r][5] += a * b1.y;
        acc[r][6] += a * b1.z; acc[r][7] += a * b1.w;
      }
    }
    __syncthreads();
  }
  float4 ba0 = ((const float4*)ba)[tx * 2];
  float4 ba1 = ((const float4*)ba)[tx * 2 + 1];
  float4 bw0 = ((const float4*)bmW)[tx * 2];
  float4 bw1 = ((const float4*)bmW)[tx * 2 + 1];
#pragma unroll
  for (int r = 0; r < 4; ++r) {
    int node = nbase + ty * 4 + r;
    if (node < NN) {
      float mk = mask[node];
      float4 o0, o1;
      o0.x = acc[r][0] + ba0.x + mk * bw0.x;
      o0.y = acc[r][1] + ba0.y + mk * bw0.y;
      o0.z = acc[r][2] + ba0.z + mk * bw0.z;
      o0.w = acc[r][3] + ba0.w + mk * bw0.w;
      o1.x = acc[r][4] + ba1.x + mk * bw1.x;
      o1.y = acc[r][5] + ba1.y + mk * bw1.y;
      o1.z = acc[r][6] + ba1.z + mk * bw1.z;
      o1.w = acc[r][7] + ba1.w + mk * bw1.w;
      o0.x = fmaxf(o0.x, 0.f); o0.y = fmaxf(o0.y, 0.f);
      o0.z = fmaxf(o0.z, 0.f); o0.w = fmaxf(o0.w, 0.f);
      o1.x = fmaxf(o1.x, 0.f); o1.y = fmaxf(o1.y, 0.f);
      o1.z = fmaxf(o1.z, 0.f); o1.w = fmaxf(o1.w, 0.f);
      *(float4*)&out[node * 64 + tx * 8] = o0;
      *(float4*)&out[node * 64 + tx * 8 + 4] = o1;
    }
  }
}

extern "C" void kernel_launch(void* const* d_in, const int* in_sizes, int n_in,
                              void* d_out, int out_size, void* d_ws, size_t ws_size,
                              hipStream_t stream) {
  const float* nf = (const float*)d_in[0];
  const float* ef = (const float*)d_in[1];
  const int*   src = (const int*)d_in[2];
  const int*   dst = (const int*)d_in[3];
  const float* Wm = (const float*)d_in[4];
  const float* bm = (const float*)d_in[5];
  const float* Wa = (const float*)d_in[6];
  const float* ba = (const float*)d_in[7];
  int*   wsi = (int*)d_ws;
  float* wsf = (float*)d_ws;
  int*   cnt   = wsi + OFF_CNT;
  int*   rs    = wsi + OFF_RS;
  int*   cur   = wsi + OFF_CUR;
  int*   bsum  = wsi + OFF_BSUM;
  int2*  einfo = (int2*)(wsi + OFF_EINFO);
  float* g     = wsf + OFF_G;
  float* Wcomb = wsf + OFF_WCOMB;
  float* bmW   = wsf + OFF_BMW;
  float* invc  = wsf + OFF_INV;
  float* mask  = wsf + OFF_MASK;
  float* out = (float*)d_out;

  hipMemsetAsync(cnt, 0, (size_t)NN * sizeof(int), stream);   // only histogram needs zeroing

  k_pre1<<<25, 256, 0, stream>>>(Wm, bm, Wa, Wcomb, bmW);
  k_hist<<<(NE / 8 + 255) / 256, 256, 0, stream>>>((const int4*)dst, cnt);
  k_scan1<<<NBLK, 256, 0, stream>>>(cnt, rs, bsum);
  k_scan2<<<1, 512, 0, stream>>>(bsum);
  k_scan3<<<NBLK, 256, 0, stream>>>(cnt, bsum, rs, cur, invc, mask);
  k_scatter<<<(NE / 8 + 255) / 256, 256, 0, stream>>>(
      (const int4*)src, (const int4*)dst, cur, einfo);
  k_gather<<<NN / 4, 256, 0, stream>>>(nf, ef, einfo, rs, g);
  k_main<<<(NN + 127) / 128, 256, 0, stream>>>(
      (const float4*)nf, (const float4*)g, invc, mask,
      (const float4*)Wcomb, bmW, ba, out);
}